// Round 13
// baseline (295.333 us; speedup 1.0000x reference)
//
#include <hip/hip_runtime.h>

// VQ-VAE vector quantizer, MI355X. N=32768 rows, D=128, K=8192 codes.
// Round 13 = r11 (proven lean two-pass, 44 VGPR) with:
//  (a) SAMPLE-max: vq_max scans only codes [0,2048) — any rowmax <= true max
//      keeps the export superset (argmin bf16-dot >= truemax-3.4e-5 >
//      samplemax-DELTA always); overflow -> proven quarter-scan fallback.
//  (b) ring-4 + prefetch-2 + COUNTED vmcnt (r5/r7-proven schedule; drain to
//      0 only at loop exit) in both passes.
// r12's 4nf tile reverted (VGPR spill: 29MB scratch writes).
// Rescore+gather unchanged (numpy-bit-exact chain, r1/r3-proven).

#define KC   8192
#define DIM  128
#define NR   32768

// d_out layout (flat, reference return order, all f32)
#define O_ZQ   0
#define O_LOSS 4194304
#define O_IDX  4194305
#define O_NSZ  4227073
#define O_NSUM 4235265
#define O_NEMB 5283841
// scratch aliases inside d_out (overwritten by later kernels):
#define O_EBF  5283844   // e_bf16 (2MB), inside O_NEMB
#define O_RMX  5808132   // rowmax u32[32768], inside O_NEMB, 16B-aligned
// cand32 u32: [row*128 + cq*32 + slot], slot<16; z_q overwrites row-by-row
// after that row's list is consumed (same-block, r10/r11-proven safe).

// ws layout (f32 index units)
#define W_LOSSP 16       // [16, 272): 256 loss buckets
#define W_CNT   8192     // u32[32768]: 4 packed u8 quarter counts
#define W_ZBF   49152    // z_bf16 (8MB), 16B-aligned
#define QCAP    16

#define DELTA    1.5e-4f   // export guard; >= 4x (2*bf16err + tie-span)
#define DWIN     64        // dot16 filter window (1.22e-4)
#define FLOATMAX 3.402823466e+38f

using short8 = __attribute__((ext_vector_type(8))) short;   // 8 bf16
using f32x4  = __attribute__((ext_vector_type(4))) float;

static __device__ __forceinline__ unsigned int pack2_bf16(float lo, float hi) {
    unsigned int ul = __builtin_bit_cast(unsigned int, lo);
    unsigned int uh = __builtin_bit_cast(unsigned int, hi);
    ul = (ul + 0x7fffu + ((ul >> 16) & 1u)) >> 16;   // RNE to bf16
    uh = (uh + 0x7fffu + ((uh >> 16) & 1u)) >> 16;
    return ul | (uh << 16);
}
// order-preserving float<->u32 map (atomicMax-able)
static __device__ __forceinline__ unsigned int enc_f32(float f) {
    unsigned int u = __builtin_bit_cast(unsigned int, f);
    return (u & 0x80000000u) ? ~u : (u | 0x80000000u);
}
static __device__ __forceinline__ float dec_f32(unsigned int u) {
    unsigned int b = (u & 0x80000000u) ? (u ^ 0x80000000u) : ~u;
    return __builtin_bit_cast(float, b);
}

// ---------------------------------------------------------------------------
// cvt + init: z->bf16 (ws), embed->bf16, seed new_size/new_sum, zero cnt,
// loss buckets, rowmax.
// ---------------------------------------------------------------------------
__global__ __launch_bounds__(256)
void vq_cvt(const float* __restrict__ z, const float* __restrict__ embed,
            const float* __restrict__ cs, const float* __restrict__ ea,
            float* __restrict__ out, float* __restrict__ ws) {
    int gid = blockIdx.x * 256 + threadIdx.x;
    if (gid < 524288) {
        const float4* s = (const float4*)z + (size_t)gid * 2;
        float4 a = s[0], b = s[1];
        uint4 wv;
        wv.x = pack2_bf16(a.x, a.y); wv.y = pack2_bf16(a.z, a.w);
        wv.z = pack2_bf16(b.x, b.y); wv.w = pack2_bf16(b.z, b.w);
        ((uint4*)(ws + W_ZBF))[gid] = wv;
    } else if (gid < 655360) {
        int j = gid - 524288;
        const float4* s = (const float4*)embed + (size_t)j * 2;
        float4 a = s[0], b = s[1];
        uint4 wv;
        wv.x = pack2_bf16(a.x, a.y); wv.y = pack2_bf16(a.z, a.w);
        wv.z = pack2_bf16(b.x, b.y); wv.w = pack2_bf16(b.z, b.w);
        ((uint4*)(out + O_EBF))[j] = wv;
    } else if (gid < 1703936) {
        int j = gid - 655360;
        out[O_NSUM + j] = 0.99f * ea[j];
    } else if (gid < 1712128) {
        int j = gid - 1703936;
        out[O_NSZ + j] = 0.99f * cs[j];
    } else if (gid < 1720320) {
        int j = gid - 1712128;
        ((uint4*)(ws + W_CNT))[j] = make_uint4(0u, 0u, 0u, 0u);
    } else if (gid < 1720576) {
        ws[W_LOSSP + (gid - 1720320)] = 0.f;
    } else if (gid < 1728768) {
        int j = gid - 1720576;
        ((uint4*)(out + O_RMX))[j] = make_uint4(0u, 0u, 0u, 0u);
    }
}

// ---------------------------------------------------------------------------
// Pass 1: SAMPLE rowmax over codes [0,2048). Grid 512: block = (rb = bid>>1,
// ch2 = bid&1) -> 128 rows x 1024 codes, 16 chunks of 64. 8 waves: chf = w&1,
// rh = w>>1 (32-row group), 2mf x 2nf. Ring-4 LDS, prefetch-2, counted vmcnt.
// Lean loop: MFMA + private fmax; one shfl-reduce + atomicMax at the end.
// ---------------------------------------------------------------------------
__global__ __launch_bounds__(512, 4)
void vq_max(const uint4* __restrict__ zb4, const uint4* __restrict__ eb4,
            unsigned int* __restrict__ rowmax) {
    __shared__ uint4 els[4 * 1024];          // 4 x 16 KiB ring

    const int t    = threadIdx.x;
    const int lane = t & 63;
    const int w    = __builtin_amdgcn_readfirstlane(t >> 6);   // 0..7
    const int g    = lane >> 4;
    const int q    = lane & 15;
    const int chf  = w & 1;
    const int rh   = w >> 1;        // 0..3
    const int rb   = blockIdx.x >> 1;
    const int ch2  = blockIdx.x & 1;     // code half of the sampled quarter
    const int row0 = rb * 128;

    const uint4* gsrc[2];
    #pragma unroll
    for (int i = 0; i < 2; ++i) {
        int s_lin = i * 512 + w * 64 + lane;
        int c = s_lin >> 4, gg = s_lin & 15;
        gsrc[i] = eb4 + (size_t)ch2 * 16384 + c * 16 + (gg ^ (c & 7));
    }

#define STAGE(CH)                                                             \
    {                                                                         \
        _Pragma("unroll")                                                     \
        for (int i = 0; i < 2; ++i)                                           \
            __builtin_amdgcn_global_load_lds(                                 \
                (const __attribute__((address_space(1))) unsigned int*)       \
                    (gsrc[i] + (size_t)(CH) * 1024),                          \
                (__attribute__((address_space(3))) unsigned int*)             \
                    &els[((CH) & 3) * 1024 + i * 512 + w * 64],               \
                16, 0, 0);                                                    \
    }

    short8 bx[2][4];
    #pragma unroll
    for (int nf = 0; nf < 2; ++nf) {
        const uint4* zp = zb4 + (size_t)(row0 + rh * 32 + nf * 16 + q) * 16;
        #pragma unroll
        for (int ks = 0; ks < 4; ++ks)
            bx[nf][ks] = __builtin_bit_cast(short8, zp[ks * 4 + g]);
    }

    STAGE(0);
    STAGE(1);

    float cmx[2] = { -FLOATMAX, -FLOATMAX };

    for (int ch = 0; ch < 16; ++ch) {
        if (ch < 14) {
            STAGE(ch + 2);
            asm volatile("s_waitcnt vmcnt(4)" ::: "memory");
        } else if (ch == 14) {
            asm volatile("s_waitcnt vmcnt(2)" ::: "memory");
        } else {
            asm volatile("s_waitcnt vmcnt(0)" ::: "memory");
        }
        __builtin_amdgcn_s_barrier();

        const uint4* el = els + (ch & 3) * 1024;

        f32x4 acc[2][2];
        #pragma unroll
        for (int mf = 0; mf < 2; ++mf)
            #pragma unroll
            for (int nf = 0; nf < 2; ++nf) acc[mf][nf] = (f32x4)0.f;

        #pragma unroll
        for (int ks = 0; ks < 4; ++ks) {
            int k8 = ks * 4 + g;
            short8 af[2];
            #pragma unroll
            for (int mf = 0; mf < 2; ++mf) {
                int cm = chf * 32 + mf * 16 + q;
                af[mf] = __builtin_bit_cast(short8, el[cm * 16 + (k8 ^ (cm & 7))]);
            }
            #pragma unroll
            for (int mf = 0; mf < 2; ++mf)
                #pragma unroll
                for (int nf = 0; nf < 2; ++nf)
                    acc[mf][nf] = __builtin_amdgcn_mfma_f32_16x16x32_bf16(
                        af[mf], bx[nf][ks], acc[mf][nf], 0, 0, 0);
        }

        #pragma unroll
        for (int nf = 0; nf < 2; ++nf)
            #pragma unroll
            for (int mf = 0; mf < 2; ++mf)
                #pragma unroll
                for (int rg = 0; rg < 4; ++rg)
                    cmx[nf] = fmaxf(cmx[nf], acc[mf][nf][rg]);
    }
#undef STAGE

    #pragma unroll
    for (int nf = 0; nf < 2; ++nf) {
        float cm = cmx[nf];
        cm = fmaxf(cm, __shfl_xor(cm, 16, 64));
        cm = fmaxf(cm, __shfl_xor(cm, 32, 64));
        if (lane < 16)
            atomicMax(&rowmax[row0 + rh * 32 + nf * 16 + lane], enc_f32(cm));
    }
}

// ---------------------------------------------------------------------------
// Pass 2: export codes with dot > rowmax - DELTA (rowmax is a LOWER bound on
// the true max -> export set is a superset of {argmin U ties}; overflow ->
// quarter-scan fallback). Grid 1024: 128 rows x 2048 codes, 32 chunks.
// Ring-4 + prefetch-2 + counted vmcnt. Exports (code | dot16<<16) staged in
// LDS, full-line flush at block end.
// ---------------------------------------------------------------------------
__global__ __launch_bounds__(512, 4)
void vq_export(const uint4* __restrict__ zb4, const uint4* __restrict__ eb4,
               const unsigned int* __restrict__ rowmax,
               unsigned int* __restrict__ cnt, unsigned int* __restrict__ candg) {
    __shared__ uint4 els[4 * 1024];               // 64 KiB ring
    __shared__ unsigned int cnt_l[128];
    __shared__ unsigned int cand_l[128 * QCAP];   // 8 KiB

    const int t    = threadIdx.x;
    const int lane = t & 63;
    const int w    = __builtin_amdgcn_readfirstlane(t >> 6);
    const int g    = lane >> 4;
    const int q    = lane & 15;
    const int chf  = w & 1;
    const int rh   = w >> 1;
    const int rb   = blockIdx.x >> 2;
    const int cq   = blockIdx.x & 3;
    const int row0 = rb * 128;

    if (t < 128) cnt_l[t] = 0u;

    const uint4* gsrc[2];
    #pragma unroll
    for (int i = 0; i < 2; ++i) {
        int s_lin = i * 512 + w * 64 + lane;
        int c = s_lin >> 4, gg = s_lin & 15;
        gsrc[i] = eb4 + (size_t)cq * 32768 + c * 16 + (gg ^ (c & 7));
    }

#define STAGE(CH)                                                             \
    {                                                                         \
        _Pragma("unroll")                                                     \
        for (int i = 0; i < 2; ++i)                                           \
            __builtin_amdgcn_global_load_lds(                                 \
                (const __attribute__((address_space(1))) unsigned int*)       \
                    (gsrc[i] + (size_t)(CH) * 1024),                          \
                (__attribute__((address_space(3))) unsigned int*)             \
                    &els[((CH) & 3) * 1024 + i * 512 + w * 64],               \
                16, 0, 0);                                                    \
    }

    short8 bx[2][4];
    float  thr[2];
    #pragma unroll
    for (int nf = 0; nf < 2; ++nf) {
        int row = row0 + rh * 32 + nf * 16 + q;
        const uint4* zp = zb4 + (size_t)row * 16;
        #pragma unroll
        for (int ks = 0; ks < 4; ++ks)
            bx[nf][ks] = __builtin_bit_cast(short8, zp[ks * 4 + g]);
        thr[nf] = dec_f32(rowmax[row]) - DELTA;
    }

    STAGE(0);
    STAGE(1);

    for (int ch = 0; ch < 32; ++ch) {
        if (ch < 30) {
            STAGE(ch + 2);
            asm volatile("s_waitcnt vmcnt(4)" ::: "memory");
        } else if (ch == 30) {
            asm volatile("s_waitcnt vmcnt(2)" ::: "memory");
        } else {
            asm volatile("s_waitcnt vmcnt(0)" ::: "memory");
        }
        __builtin_amdgcn_s_barrier();

        const uint4* el = els + (ch & 3) * 1024;

        f32x4 acc[2][2];
        #pragma unroll
        for (int mf = 0; mf < 2; ++mf)
            #pragma unroll
            for (int nf = 0; nf < 2; ++nf) acc[mf][nf] = (f32x4)0.f;

        #pragma unroll
        for (int ks = 0; ks < 4; ++ks) {
            int k8 = ks * 4 + g;
            short8 af[2];
            #pragma unroll
            for (int mf = 0; mf < 2; ++mf) {
                int cm = chf * 32 + mf * 16 + q;
                af[mf] = __builtin_bit_cast(short8, el[cm * 16 + (k8 ^ (cm & 7))]);
            }
            #pragma unroll
            for (int mf = 0; mf < 2; ++mf)
                #pragma unroll
                for (int nf = 0; nf < 2; ++nf)
                    acc[mf][nf] = __builtin_amdgcn_mfma_f32_16x16x32_bf16(
                        af[mf], bx[nf][ks], acc[mf][nf], 0, 0, 0);
        }

        // per-lane check against the threshold; export is rare
        #pragma unroll
        for (int nf = 0; nf < 2; ++nf) {
            float cm = -FLOATMAX;
            #pragma unroll
            for (int mf = 0; mf < 2; ++mf)
                #pragma unroll
                for (int rg = 0; rg < 4; ++rg) cm = fmaxf(cm, acc[mf][nf][rg]);
            if (cm > thr[nf]) {
                int r_l = rh * 32 + nf * 16 + q;
                #pragma unroll
                for (int mf = 0; mf < 2; ++mf)
                    #pragma unroll
                    for (int rg = 0; rg < 4; ++rg) {
                        if (acc[mf][nf][rg] > thr[nf]) {
                            int code = cq * 2048 + ch * 64 + chf * 32
                                     + mf * 16 + g * 4 + rg;
                            unsigned int dot16 = (unsigned int)(int)
                                fmaf(acc[mf][nf][rg], 524288.0f, 32768.0f);
                            unsigned int slot = atomicAdd(&cnt_l[r_l], 1u);
                            if (slot < QCAP)
                                cand_l[r_l * QCAP + slot] =
                                    (unsigned int)code | (dot16 << 16);
                        }
                    }
            }
        }
    }
#undef STAGE

    __syncthreads();
    // flush: 128 rows x 16 u32 = 512 uint4; one full 64B line per row-quarter
    {
        int r_l = t >> 2, part = t & 3;
        *(uint4*)&candg[(size_t)(row0 + r_l) * 128 + cq * 32 + part * 4] =
            ((uint4*)cand_l)[t];
    }
    if (t < 128) {
        unsigned int v = min(cnt_l[t], (unsigned int)(QCAP + 1));
        atomicAdd(&cnt[row0 + t], v << (8 * (unsigned)cq));
    }
}

// ---------------------------------------------------------------------------
// Phase 2 (merged): dot16 filter -> exact rescore (numpy-bit-exact,
// r1/r3-proven) of survivors -> idx, z_q, loss partial, EMA stats.
// Overflowed quarter -> exact scan of its 2048 codes.
// ---------------------------------------------------------------------------
__global__ __launch_bounds__(256)
void vq_rescore_gather(const float* __restrict__ z,
                       const float* __restrict__ embed,
                       const unsigned int* __restrict__ cnt,
                       const unsigned int* __restrict__ candg,
                       float* __restrict__ out, float* __restrict__ ws) {
    __shared__ float xr[4][128];
    __shared__ float lsh[4];
    const int t = threadIdx.x, w = t >> 6, lane = t & 63;
    const int row = blockIdx.x * 4 + w;

    ((float2*)xr[w])[lane] = ((const float2*)(z + (size_t)row * DIM))[lane];
    __syncthreads();

    const float4* x4 = (const float4*)xr[w];

    float s1n;
    {
        #pragma clang fp contract(off)
        float r8[8];
        float4 a = x4[0], b = x4[1];
        r8[0] = a.x * a.x; r8[1] = a.y * a.y; r8[2] = a.z * a.z; r8[3] = a.w * a.w;
        r8[4] = b.x * b.x; r8[5] = b.y * b.y; r8[6] = b.z * b.z; r8[7] = b.w * b.w;
        for (int bb = 1; bb < 16; ++bb) {
            float4 c = x4[2 * bb], d = x4[2 * bb + 1];
            r8[0] += c.x * c.x; r8[1] += c.y * c.y; r8[2] += c.z * c.z; r8[3] += c.w * c.w;
            r8[4] += d.x * d.x; r8[5] += d.y * d.y; r8[6] += d.z * d.z; r8[7] += d.w * d.w;
        }
        s1n = ((r8[0] + r8[1]) + (r8[2] + r8[3])) + ((r8[4] + r8[5]) + (r8[6] + r8[7]));
    }

    float bd = FLOATMAX;
    int   bi = 0x7fffffff;

#define EVAL_CODE(code_)                                                      \
    {                                                                         \
        const float4* ep = (const float4*)(embed + (size_t)(code_) * DIM);    \
        float dot = 0.f;                                                      \
        _Pragma("unroll 8")                                                   \
        for (int k4 = 0; k4 < 32; ++k4) {                                     \
            float4 xv = x4[k4], ev = ep[k4];                                  \
            dot = fmaf(xv.x, ev.x, dot);                                      \
            dot = fmaf(xv.y, ev.y, dot);                                      \
            dot = fmaf(xv.z, ev.z, dot);                                      \
            dot = fmaf(xv.w, ev.w, dot);                                      \
        }                                                                     \
        float d = fmaf(-2.0f, dot, s1n);                                      \
        if (d < bd || (d == bd && (code_) < bi)) { bd = d; bi = (code_); }    \
    }

    const unsigned int v = cnt[row];
    int  cq4[4];
    bool ovf[4];
    #pragma unroll
    for (int qq = 0; qq < 4; ++qq) {
        cq4[qq] = (int)((v >> (8 * qq)) & 0xffu);
        ovf[qq] = (cq4[qq] > QCAP);
    }

    const unsigned int* cl = candg + (size_t)row * 128;

    // one entry per lane: qq = lane>>4, slot = lane&15
    int qq0 = lane >> 4, sl0 = lane & 15;
    bool v0 = (!ovf[qq0]) && (sl0 < cq4[qq0]);
    unsigned int p0 = v0 ? cl[qq0 * 32 + sl0] : 0u;
    int d0 = v0 ? (int)(p0 >> 16) : -1;

    int m = d0;
    #pragma unroll
    for (int o = 32; o >= 1; o >>= 1) m = max(m, __shfl_xor(m, o, 64));

    if (v0 && d0 + DWIN >= m) { int code = (int)(p0 & 0xffffu); EVAL_CODE(code); }

    #pragma unroll
    for (int qq = 0; qq < 4; ++qq) {
        if (ovf[qq]) {
            for (int j = lane; j < 2048; j += 64) {
                int code = qq * 2048 + j;
                EVAL_CODE(code);
            }
        }
    }
#undef EVAL_CODE

    #pragma unroll
    for (int o = 32; o >= 1; o >>= 1) {
        float d2 = __shfl_xor(bd, o, 64);
        int   i2 = __shfl_xor(bi, o, 64);
        if (d2 < bd || (d2 == bd && i2 < bi)) { bd = d2; bi = i2; }
    }

    float2 zv2 = ((const float2*)xr[w])[lane];
    float2 ev2 = ((const float2*)(embed + (size_t)bi * DIM))[lane];
    float2 o2;
    o2.x = zv2.x + (ev2.x - zv2.x);     // z + (z_q - z), np op order
    o2.y = zv2.y + (ev2.y - zv2.y);
    ((float2*)(out + O_ZQ))[(size_t)row * 64 + lane] = o2;

    float dx = zv2.x - ev2.x, dy = zv2.y - ev2.y;
    float lp = dx * dx + dy * dy;
    #pragma unroll
    for (int off = 32; off >= 1; off >>= 1) lp += __shfl_down(lp, off, 64);

    atomicAdd(&out[O_NSUM + (size_t)bi * DIM + lane * 2],     0.01f * zv2.x);
    atomicAdd(&out[O_NSUM + (size_t)bi * DIM + lane * 2 + 1], 0.01f * zv2.y);
    if (lane == 0) {
        out[O_IDX + row] = (float)bi;
        atomicAdd(&out[O_NSZ + bi], 0.01f);
        lsh[w] = lp;
    }
    __syncthreads();
    if (t == 0)
        atomicAdd(&ws[W_LOSSP + (blockIdx.x & 255)],
                  (lsh[0] + lsh[1]) + (lsh[2] + lsh[3]));
}

// ---------------------------------------------------------------------------
// finalize: n = sum(new_size) -> ws[1]; loss = sum(256 buckets)/(N*D)
// ---------------------------------------------------------------------------
__global__ __launch_bounds__(256)
void vq_finalize(float* __restrict__ out, float* __restrict__ ws) {
    __shared__ float sh[256];
    const int t = threadIdx.x;

    float s = 0.f;
    for (int i = t; i < KC; i += 256) s += out[O_NSZ + i];
    sh[t] = s; __syncthreads();
    for (int o = 128; o > 0; o >>= 1) {
        if (t < o) sh[t] += sh[t + o];
        __syncthreads();
    }
    float n = sh[0];
    __syncthreads();

    sh[t] = ws[W_LOSSP + t]; __syncthreads();
    for (int o = 128; o > 0; o >>= 1) {
        if (t < o) sh[t] += sh[t + o];
        __syncthreads();
    }
    if (t == 0) {
        ws[1] = n;
        out[O_LOSS] = sh[0] / 4194304.0f;
    }
}

__global__ __launch_bounds__(256)
void vq_new_embed(float* __restrict__ out, const float* __restrict__ ws) {
    int i = blockIdx.x * 256 + threadIdx.x;
    if (i >= KC * DIM) return;
    int k = i >> 7;
    float n  = ws[1];
    float ns = out[O_NSZ + k];
    float sm = (ns + 1e-5f) / (n + 0.08192f) * n;
    out[O_NEMB + i] = out[O_NSUM + i] / sm;
}

extern "C" void kernel_launch(void* const* d_in, const int* in_sizes, int n_in,
                              void* d_out, int out_size, void* d_ws, size_t ws_size,
                              hipStream_t stream) {
    const float* z     = (const float*)d_in[0];
    const float* embed = (const float*)d_in[1];
    const float* cs    = (const float*)d_in[2];
    const float* ea    = (const float*)d_in[3];
    float* out = (float*)d_out;
    float* ws  = (float*)d_ws;
    unsigned int* cnt    = (unsigned int*)(ws + W_CNT);
    unsigned int* candg  = (unsigned int*)out;          // O_ZQ region
    unsigned int* rowmax = (unsigned int*)(out + O_RMX);

    vq_cvt<<<6753, 256, 0, stream>>>(z, embed, cs, ea, out, ws);
    vq_max<<<512, 512, 0, stream>>>((const uint4*)(ws + W_ZBF),
                                    (const uint4*)(out + O_EBF), rowmax);
    vq_export<<<1024, 512, 0, stream>>>((const uint4*)(ws + W_ZBF),
                                        (const uint4*)(out + O_EBF),
                                        rowmax, cnt, candg);
    vq_rescore_gather<<<NR / 4, 256, 0, stream>>>(z, embed, cnt, candg, out, ws);
    vq_finalize<<<1, 256, 0, stream>>>(out, ws);
    vq_new_embed<<<4096, 256, 0, stream>>>(out, ws);
}

// Round 15
// 223.550 us; speedup vs baseline: 1.3211x; 1.3211x over previous
//
#include <hip/hip_runtime.h>

// VQ-VAE vector quantizer, MI355X. N=32768 rows, D=128, K=8192 codes.
// Round 15 = r14 with the global_load_lds LDS DEST made wave-uniform
// (r14 passed a lane-varying pointer -> GPU fault; HW adds lane*16B itself,
// rule #21/m104). 2mf x 4nf per wave at 256 thr, __launch_bounds__(256,3):
// 4:1 MFMA:ds_read without r12's VGPR spill. Full rowmax (r13 sample-max
// stays reverted). Rescore+gather unchanged (numpy-bit-exact, r1/r3-proven).

#define KC   8192
#define DIM  128
#define NR   32768

// d_out layout (flat, reference return order, all f32)
#define O_ZQ   0
#define O_LOSS 4194304
#define O_IDX  4194305
#define O_NSZ  4227073
#define O_NSUM 4235265
#define O_NEMB 5283841
// scratch aliases inside d_out (overwritten by later kernels):
#define O_EBF  5283844   // e_bf16 (2MB), inside O_NEMB
#define O_RMX  5808132   // rowmax u32[32768], inside O_NEMB, 16B-aligned
// cand32 u32: [row*128 + cq*32 + slot], slot<16; z_q overwrites row-by-row
// after that row's list is consumed (same-block, r10/r11-proven safe).

// ws layout (f32 index units)
#define W_LOSSP 16       // [16, 272): 256 loss buckets
#define W_CNT   8192     // u32[32768]: 4 packed u8 quarter counts
#define W_ZBF   49152    // z_bf16 (8MB), 16B-aligned
#define QCAP    16

#define DELTA    1.5e-4f   // export guard; >= 4x (2*bf16err + tie-span)
#define DWIN     64        // dot16 filter window (1.22e-4)
#define FLOATMAX 3.402823466e+38f

using short8 = __attribute__((ext_vector_type(8))) short;   // 8 bf16
using f32x4  = __attribute__((ext_vector_type(4))) float;

static __device__ __forceinline__ unsigned int pack2_bf16(float lo, float hi) {
    unsigned int ul = __builtin_bit_cast(unsigned int, lo);
    unsigned int uh = __builtin_bit_cast(unsigned int, hi);
    ul = (ul + 0x7fffu + ((ul >> 16) & 1u)) >> 16;   // RNE to bf16
    uh = (uh + 0x7fffu + ((uh >> 16) & 1u)) >> 16;
    return ul | (uh << 16);
}
// order-preserving float<->u32 map (atomicMax-able)
static __device__ __forceinline__ unsigned int enc_f32(float f) {
    unsigned int u = __builtin_bit_cast(unsigned int, f);
    return (u & 0x80000000u) ? ~u : (u | 0x80000000u);
}
static __device__ __forceinline__ float dec_f32(unsigned int u) {
    unsigned int b = (u & 0x80000000u) ? (u ^ 0x80000000u) : ~u;
    return __builtin_bit_cast(float, b);
}

// ---------------------------------------------------------------------------
// cvt + init: z->bf16 (ws), embed->bf16, seed new_size/new_sum, zero cnt,
// loss buckets, rowmax.
// ---------------------------------------------------------------------------
__global__ __launch_bounds__(256)
void vq_cvt(const float* __restrict__ z, const float* __restrict__ embed,
            const float* __restrict__ cs, const float* __restrict__ ea,
            float* __restrict__ out, float* __restrict__ ws) {
    int gid = blockIdx.x * 256 + threadIdx.x;
    if (gid < 524288) {
        const float4* s = (const float4*)z + (size_t)gid * 2;
        float4 a = s[0], b = s[1];
        uint4 wv;
        wv.x = pack2_bf16(a.x, a.y); wv.y = pack2_bf16(a.z, a.w);
        wv.z = pack2_bf16(b.x, b.y); wv.w = pack2_bf16(b.z, b.w);
        ((uint4*)(ws + W_ZBF))[gid] = wv;
    } else if (gid < 655360) {
        int j = gid - 524288;
        const float4* s = (const float4*)embed + (size_t)j * 2;
        float4 a = s[0], b = s[1];
        uint4 wv;
        wv.x = pack2_bf16(a.x, a.y); wv.y = pack2_bf16(a.z, a.w);
        wv.z = pack2_bf16(b.x, b.y); wv.w = pack2_bf16(b.z, b.w);
        ((uint4*)(out + O_EBF))[j] = wv;
    } else if (gid < 1703936) {
        int j = gid - 655360;
        out[O_NSUM + j] = 0.99f * ea[j];
    } else if (gid < 1712128) {
        int j = gid - 1703936;
        out[O_NSZ + j] = 0.99f * cs[j];
    } else if (gid < 1720320) {
        int j = gid - 1712128;
        ((uint4*)(ws + W_CNT))[j] = make_uint4(0u, 0u, 0u, 0u);
    } else if (gid < 1720576) {
        ws[W_LOSSP + (gid - 1720320)] = 0.f;
    } else if (gid < 1728768) {
        int j = gid - 1720576;
        ((uint4*)(out + O_RMX))[j] = make_uint4(0u, 0u, 0u, 0u);
    }
}

// ---------------------------------------------------------------------------
// Pass 1: FULL per-row max bf16-dot. Grid 1024: block = (rb = bid>>2,
// cq = bid&3) -> 128 rows x 2048 codes, 32 chunks of 64. 4 waves (256 thr):
// chf = w&1, rh = w>>1 (64-row half); per wave 2mf x 4nf (0.25 reads/MFMA).
// Dbuf LDS via global_load_lds (WAVE-UNIFORM dest base, per-lane global
// src), vmcnt(0)+barrier at iter end.
// ---------------------------------------------------------------------------
__global__ __launch_bounds__(256, 3)
void vq_max(const uint4* __restrict__ zb4, const uint4* __restrict__ eb4,
            unsigned int* __restrict__ rowmax) {
    __shared__ uint4 els[2 * 1024];          // 32 KiB dbuf

    const int t    = threadIdx.x;
    const int lane = t & 63;
    const int w    = __builtin_amdgcn_readfirstlane(t >> 6);   // 0..3
    const int g    = lane >> 4;
    const int q    = lane & 15;
    const int chf  = w & 1;
    const int rh   = w >> 1;        // 0..1
    const int rb   = blockIdx.x >> 2;
    const int cq   = blockIdx.x & 3;
    const int row0 = rb * 128;

    const uint4* gsrc[4];
    #pragma unroll
    for (int i = 0; i < 4; ++i) {
        int s_lin = i * 256 + t;            // 0..1023 (per-lane global src)
        int c = s_lin >> 4, gg = s_lin & 15;
        gsrc[i] = eb4 + (size_t)cq * 32768 + c * 16 + (gg ^ (c & 7));
    }

#define STAGE(CH)                                                             \
    {                                                                         \
        _Pragma("unroll")                                                     \
        for (int i = 0; i < 4; ++i)                                           \
            __builtin_amdgcn_global_load_lds(                                 \
                (const __attribute__((address_space(1))) unsigned int*)       \
                    (gsrc[i] + (size_t)(CH) * 1024),                          \
                (__attribute__((address_space(3))) unsigned int*)             \
                    &els[((CH) & 1) * 1024 + i * 256 + (w << 6)],             \
                16, 0, 0);                                                    \
    }

    short8 bx[4][4];
    #pragma unroll
    for (int nf = 0; nf < 4; ++nf) {
        const uint4* zp = zb4 + (size_t)(row0 + rh * 64 + nf * 16 + q) * 16;
        #pragma unroll
        for (int ks = 0; ks < 4; ++ks)
            bx[nf][ks] = __builtin_bit_cast(short8, zp[ks * 4 + g]);
    }

    STAGE(0);
    asm volatile("s_waitcnt vmcnt(0)" ::: "memory");
    __builtin_amdgcn_s_barrier();

    float cmx[4] = { -FLOATMAX, -FLOATMAX, -FLOATMAX, -FLOATMAX };

    for (int ch = 0; ch < 32; ++ch) {
        if (ch < 31) STAGE(ch + 1);

        const uint4* el = els + (ch & 1) * 1024;

        f32x4 acc[2][4];
        #pragma unroll
        for (int mf = 0; mf < 2; ++mf)
            #pragma unroll
            for (int nf = 0; nf < 4; ++nf) acc[mf][nf] = (f32x4)0.f;

        #pragma unroll
        for (int ks = 0; ks < 4; ++ks) {
            int k8 = ks * 4 + g;
            short8 af[2];
            #pragma unroll
            for (int mf = 0; mf < 2; ++mf) {
                int cm = chf * 32 + mf * 16 + q;
                af[mf] = __builtin_bit_cast(short8, el[cm * 16 + (k8 ^ (cm & 7))]);
            }
            #pragma unroll
            for (int mf = 0; mf < 2; ++mf)
                #pragma unroll
                for (int nf = 0; nf < 4; ++nf)
                    acc[mf][nf] = __builtin_amdgcn_mfma_f32_16x16x32_bf16(
                        af[mf], bx[nf][ks], acc[mf][nf], 0, 0, 0);
        }

        #pragma unroll
        for (int nf = 0; nf < 4; ++nf)
            #pragma unroll
            for (int mf = 0; mf < 2; ++mf)
                #pragma unroll
                for (int rg = 0; rg < 4; ++rg)
                    cmx[nf] = fmaxf(cmx[nf], acc[mf][nf][rg]);

        asm volatile("s_waitcnt vmcnt(0)" ::: "memory");
        __builtin_amdgcn_s_barrier();
    }
#undef STAGE

    #pragma unroll
    for (int nf = 0; nf < 4; ++nf) {
        float cm = cmx[nf];
        cm = fmaxf(cm, __shfl_xor(cm, 16, 64));
        cm = fmaxf(cm, __shfl_xor(cm, 32, 64));
        if (lane < 16)
            atomicMax(&rowmax[row0 + rh * 64 + nf * 16 + lane], enc_f32(cm));
    }
}

// ---------------------------------------------------------------------------
// Pass 2: export codes with dot > rowmax - DELTA (rowmax = TRUE max ->
// exports superset of {argmin U ties}; overflow -> quarter-scan fallback).
// Same tiling/MFMA as vq_max (dots bit-identical). Exports (code|dot16<<16)
// staged in LDS, full-line flush at block end.
// ---------------------------------------------------------------------------
__global__ __launch_bounds__(256, 3)
void vq_export(const uint4* __restrict__ zb4, const uint4* __restrict__ eb4,
               const unsigned int* __restrict__ rowmax,
               unsigned int* __restrict__ cnt, unsigned int* __restrict__ candg) {
    __shared__ uint4 els[2 * 1024];               // 32 KiB dbuf
    __shared__ unsigned int cnt_l[128];
    __shared__ unsigned int cand_l[128 * QCAP];   // 8 KiB

    const int t    = threadIdx.x;
    const int lane = t & 63;
    const int w    = __builtin_amdgcn_readfirstlane(t >> 6);   // 0..3
    const int g    = lane >> 4;
    const int q    = lane & 15;
    const int chf  = w & 1;
    const int rh   = w >> 1;        // 0..1
    const int rb   = blockIdx.x >> 2;
    const int cq   = blockIdx.x & 3;
    const int row0 = rb * 128;

    if (t < 128) cnt_l[t] = 0u;

    const uint4* gsrc[4];
    #pragma unroll
    for (int i = 0; i < 4; ++i) {
        int s_lin = i * 256 + t;
        int c = s_lin >> 4, gg = s_lin & 15;
        gsrc[i] = eb4 + (size_t)cq * 32768 + c * 16 + (gg ^ (c & 7));
    }

#define STAGE(CH)                                                             \
    {                                                                         \
        _Pragma("unroll")                                                     \
        for (int i = 0; i < 4; ++i)                                           \
            __builtin_amdgcn_global_load_lds(                                 \
                (const __attribute__((address_space(1))) unsigned int*)       \
                    (gsrc[i] + (size_t)(CH) * 1024),                          \
                (__attribute__((address_space(3))) unsigned int*)             \
                    &els[((CH) & 1) * 1024 + i * 256 + (w << 6)],             \
                16, 0, 0);                                                    \
    }

    short8 bx[4][4];
    float  thr[4];
    #pragma unroll
    for (int nf = 0; nf < 4; ++nf) {
        int row = row0 + rh * 64 + nf * 16 + q;
        const uint4* zp = zb4 + (size_t)row * 16;
        #pragma unroll
        for (int ks = 0; ks < 4; ++ks)
            bx[nf][ks] = __builtin_bit_cast(short8, zp[ks * 4 + g]);
        thr[nf] = dec_f32(rowmax[row]) - DELTA;
    }

    STAGE(0);
    asm volatile("s_waitcnt vmcnt(0)" ::: "memory");
    __builtin_amdgcn_s_barrier();

    for (int ch = 0; ch < 32; ++ch) {
        if (ch < 31) STAGE(ch + 1);

        const uint4* el = els + (ch & 1) * 1024;

        f32x4 acc[2][4];
        #pragma unroll
        for (int mf = 0; mf < 2; ++mf)
            #pragma unroll
            for (int nf = 0; nf < 4; ++nf) acc[mf][nf] = (f32x4)0.f;

        #pragma unroll
        for (int ks = 0; ks < 4; ++ks) {
            int k8 = ks * 4 + g;
            short8 af[2];
            #pragma unroll
            for (int mf = 0; mf < 2; ++mf) {
                int cm = chf * 32 + mf * 16 + q;
                af[mf] = __builtin_bit_cast(short8, el[cm * 16 + (k8 ^ (cm & 7))]);
            }
            #pragma unroll
            for (int mf = 0; mf < 2; ++mf)
                #pragma unroll
                for (int nf = 0; nf < 4; ++nf)
                    acc[mf][nf] = __builtin_amdgcn_mfma_f32_16x16x32_bf16(
                        af[mf], bx[nf][ks], acc[mf][nf], 0, 0, 0);
        }

        // per-lane check against the FINAL threshold; export is rare
        #pragma unroll
        for (int nf = 0; nf < 4; ++nf) {
            float cm = -FLOATMAX;
            #pragma unroll
            for (int mf = 0; mf < 2; ++mf)
                #pragma unroll
                for (int rg = 0; rg < 4; ++rg) cm = fmaxf(cm, acc[mf][nf][rg]);
            if (cm > thr[nf]) {
                int r_l = rh * 64 + nf * 16 + q;
                #pragma unroll
                for (int mf = 0; mf < 2; ++mf)
                    #pragma unroll
                    for (int rg = 0; rg < 4; ++rg) {
                        if (acc[mf][nf][rg] > thr[nf]) {
                            int code = cq * 2048 + ch * 64 + chf * 32
                                     + mf * 16 + g * 4 + rg;
                            unsigned int dot16 = (unsigned int)(int)
                                fmaf(acc[mf][nf][rg], 524288.0f, 32768.0f);
                            unsigned int slot = atomicAdd(&cnt_l[r_l], 1u);
                            if (slot < QCAP)
                                cand_l[r_l * QCAP + slot] =
                                    (unsigned int)code | (dot16 << 16);
                        }
                    }
            }
        }

        asm volatile("s_waitcnt vmcnt(0)" ::: "memory");
        __builtin_amdgcn_s_barrier();
    }
#undef STAGE

    __syncthreads();
    // flush: 128 rows x 16 u32 = 512 uint4; full 64B line per row-quarter
    #pragma unroll
    for (int i = 0; i < 2; ++i) {
        int idx = t + i * 256;               // uint4 index 0..511
        int r_l = idx >> 2, part = idx & 3;
        *(uint4*)&candg[(size_t)(row0 + r_l) * 128 + cq * 32 + part * 4] =
            ((uint4*)cand_l)[idx];
    }
    if (t < 128) {
        unsigned int v = min(cnt_l[t], (unsigned int)(QCAP + 1));
        atomicAdd(&cnt[row0 + t], v << (8 * (unsigned)cq));
    }
}

// ---------------------------------------------------------------------------
// Phase 2 (merged): dot16 filter -> exact rescore (numpy-bit-exact,
// r1/r3-proven) of survivors -> idx, z_q, loss partial, EMA stats.
// Overflowed quarter -> exact scan of its 2048 codes.
// ---------------------------------------------------------------------------
__global__ __launch_bounds__(256)
void vq_rescore_gather(const float* __restrict__ z,
                       const float* __restrict__ embed,
                       const unsigned int* __restrict__ cnt,
                       const unsigned int* __restrict__ candg,
                       float* __restrict__ out, float* __restrict__ ws) {
    __shared__ float xr[4][128];
    __shared__ float lsh[4];
    const int t = threadIdx.x, w = t >> 6, lane = t & 63;
    const int row = blockIdx.x * 4 + w;

    ((float2*)xr[w])[lane] = ((const float2*)(z + (size_t)row * DIM))[lane];
    __syncthreads();

    const float4* x4 = (const float4*)xr[w];

    float s1n;
    {
        #pragma clang fp contract(off)
        float r8[8];
        float4 a = x4[0], b = x4[1];
        r8[0] = a.x * a.x; r8[1] = a.y * a.y; r8[2] = a.z * a.z; r8[3] = a.w * a.w;
        r8[4] = b.x * b.x; r8[5] = b.y * b.y; r8[6] = b.z * b.z; r8[7] = b.w * b.w;
        for (int bb = 1; bb < 16; ++bb) {
            float4 c = x4[2 * bb], d = x4[2 * bb + 1];
            r8[0] += c.x * c.x; r8[1] += c.y * c.y; r8[2] += c.z * c.z; r8[3] += c.w * c.w;
            r8[4] += d.x * d.x; r8[5] += d.y * d.y; r8[6] += d.z * d.z; r8[7] += d.w * d.w;
        }
        s1n = ((r8[0] + r8[1]) + (r8[2] + r8[3])) + ((r8[4] + r8[5]) + (r8[6] + r8[7]));
    }

    float bd = FLOATMAX;
    int   bi = 0x7fffffff;

#define EVAL_CODE(code_)                                                      \
    {                                                                         \
        const float4* ep = (const float4*)(embed + (size_t)(code_) * DIM);    \
        float dot = 0.f;                                                      \
        _Pragma("unroll 8")                                                   \
        for (int k4 = 0; k4 < 32; ++k4) {                                     \
            float4 xv = x4[k4], ev = ep[k4];                                  \
            dot = fmaf(xv.x, ev.x, dot);                                      \
            dot = fmaf(xv.y, ev.y, dot);                                      \
            dot = fmaf(xv.z, ev.z, dot);                                      \
            dot = fmaf(xv.w, ev.w, dot);                                      \
        }                                                                     \
        float d = fmaf(-2.0f, dot, s1n);                                      \
        if (d < bd || (d == bd && (code_) < bi)) { bd = d; bi = (code_); }    \
    }

    const unsigned int v = cnt[row];
    int  cq4[4];
    bool ovf[4];
    #pragma unroll
    for (int qq = 0; qq < 4; ++qq) {
        cq4[qq] = (int)((v >> (8 * qq)) & 0xffu);
        ovf[qq] = (cq4[qq] > QCAP);
    }

    const unsigned int* cl = candg + (size_t)row * 128;

    // one entry per lane: qq = lane>>4, slot = lane&15
    int qq0 = lane >> 4, sl0 = lane & 15;
    bool v0 = (!ovf[qq0]) && (sl0 < cq4[qq0]);
    unsigned int p0 = v0 ? cl[qq0 * 32 + sl0] : 0u;
    int d0 = v0 ? (int)(p0 >> 16) : -1;

    int m = d0;
    #pragma unroll
    for (int o = 32; o >= 1; o >>= 1) m = max(m, __shfl_xor(m, o, 64));

    if (v0 && d0 + DWIN >= m) { int code = (int)(p0 & 0xffffu); EVAL_CODE(code); }

    #pragma unroll
    for (int qq = 0; qq < 4; ++qq) {
        if (ovf[qq]) {
            for (int j = lane; j < 2048; j += 64) {
                int code = qq * 2048 + j;
                EVAL_CODE(code);
            }
        }
    }
#undef EVAL_CODE

    #pragma unroll
    for (int o = 32; o >= 1; o >>= 1) {
        float d2 = __shfl_xor(bd, o, 64);
        int   i2 = __shfl_xor(bi, o, 64);
        if (d2 < bd || (d2 == bd && i2 < bi)) { bd = d2; bi = i2; }
    }

    float2 zv2 = ((const float2*)xr[w])[lane];
    float2 ev2 = ((const float2*)(embed + (size_t)bi * DIM))[lane];
    float2 o2;
    o2.x = zv2.x + (ev2.x - zv2.x);     // z + (z_q - z), np op order
    o2.y = zv2.y + (ev2.y - zv2.y);
    ((float2*)(out + O_ZQ))[(size_t)row * 64 + lane] = o2;

    float dx = zv2.x - ev2.x, dy = zv2.y - ev2.y;
    float lp = dx * dx + dy * dy;
    #pragma unroll
    for (int off = 32; off >= 1; off >>= 1) lp += __shfl_down(lp, off, 64);

    atomicAdd(&out[O_NSUM + (size_t)bi * DIM + lane * 2],     0.01f * zv2.x);
    atomicAdd(&out[O_NSUM + (size_t)bi * DIM + lane * 2 + 1], 0.01f * zv2.y);
    if (lane == 0) {
        out[O_IDX + row] = (float)bi;
        atomicAdd(&out[O_NSZ + bi], 0.01f);
        lsh[w] = lp;
    }
    __syncthreads();
    if (t == 0)
        atomicAdd(&ws[W_LOSSP + (blockIdx.x & 255)],
                  (lsh[0] + lsh[1]) + (lsh[2] + lsh[3]));
}

// ---------------------------------------------------------------------------
// finalize: n = sum(new_size) -> ws[1]; loss = sum(256 buckets)/(N*D)
// ---------------------------------------------------------------------------
__global__ __launch_bounds__(256)
void vq_finalize(float* __restrict__ out, float* __restrict__ ws) {
    __shared__ float sh[256];
    const int t = threadIdx.x;

    float s = 0.f;
    for (int i = t; i < KC; i += 256) s += out[O_NSZ + i];
    sh[t] = s; __syncthreads();
    for (int o = 128; o > 0; o >>= 1) {
        if (t < o) sh[t] += sh[t + o];
        __syncthreads();
    }
    float n = sh[0];
    __syncthreads();

    sh[t] = ws[W_LOSSP + t]; __syncthreads();
    for (int o = 128; o > 0; o >>= 1) {
        if (t < o) sh[t] += sh[t + o];
        __syncthreads();
    }
    if (t == 0) {
        ws[1] = n;
        out[O_LOSS] = sh[0] / 4194304.0f;
    }
}

__global__ __launch_bounds__(256)
void vq_new_embed(float* __restrict__ out, const float* __restrict__ ws) {
    int i = blockIdx.x * 256 + threadIdx.x;
    if (i >= KC * DIM) return;
    int k = i >> 7;
    float n  = ws[1];
    float ns = out[O_NSZ + k];
    float sm = (ns + 1e-5f) / (n + 0.08192f) * n;
    out[O_NEMB + i] = out[O_NSUM + i] / sm;
}

extern "C" void kernel_launch(void* const* d_in, const int* in_sizes, int n_in,
                              void* d_out, int out_size, void* d_ws, size_t ws_size,
                              hipStream_t stream) {
    const float* z     = (const float*)d_in[0];
    const float* embed = (const float*)d_in[1];
    const float* cs    = (const float*)d_in[2];
    const float* ea    = (const float*)d_in[3];
    float* out = (float*)d_out;
    float* ws  = (float*)d_ws;
    unsigned int* cnt    = (unsigned int*)(ws + W_CNT);
    unsigned int* candg  = (unsigned int*)out;          // O_ZQ region
    unsigned int* rowmax = (unsigned int*)(out + O_RMX);

    vq_cvt<<<6753, 256, 0, stream>>>(z, embed, cs, ea, out, ws);
    vq_max<<<1024, 256, 0, stream>>>((const uint4*)(ws + W_ZBF),
                                     (const uint4*)(out + O_EBF), rowmax);
    vq_export<<<1024, 256, 0, stream>>>((const uint4*)(ws + W_ZBF),
                                        (const uint4*)(out + O_EBF),
                                        rowmax, cnt, candg);
    vq_rescore_gather<<<NR / 4, 256, 0, stream>>>(z, embed, cnt, candg, out, ws);
    vq_finalize<<<1, 256, 0, stream>>>(out, ws);
    vq_new_embed<<<4096, 256, 0, stream>>>(out, ws);
}

// Round 16
// 222.181 us; speedup vs baseline: 1.3292x; 1.0062x over previous
//
#include <hip/hip_runtime.h>

// VQ-VAE vector quantizer, MI355X. N=32768 rows, D=128, K=8192 codes.
// Round 16: both screen passes restored to r7's proven schedule (the only
// config that ran the full MFMA volume in ~62 us): 512 thr / 8 waves,
// 2mf x 4nf, 256 rows x 2048 codes per block, ring-4 LDS + prefetch-2 +
// COUNTED vmcnt(4/2/0) (r10-r15 drained vmcnt(0) per chunk -- the prefetch
// never overlapped compute), setprio around MFMA, launch_bounds(512,2)
// (r12's (512,4) forced a 64-VGPR cap -> spill). Export: full-max threshold
// (r11/r15-proven), direct scattered global stores (~2/row; r7 proved no
// overfetch). cvt / rescore+gather / finalize verbatim r15 (proven).

#define KC   8192
#define DIM  128
#define NR   32768

// d_out layout (flat, reference return order, all f32)
#define O_ZQ   0
#define O_LOSS 4194304
#define O_IDX  4194305
#define O_NSZ  4227073
#define O_NSUM 4235265
#define O_NEMB 5283841
// scratch aliases inside d_out (overwritten by later kernels):
#define O_EBF  5283844   // e_bf16 (2MB), inside O_NEMB
#define O_RMX  5808132   // rowmax u32[32768], inside O_NEMB, 16B-aligned
// cand32 u32: [row*128 + cq*32 + slot], slot<16; z_q overwrites row-by-row
// after that row's list is consumed (same-block, r10/r11-proven safe).

// ws layout (f32 index units)
#define W_LOSSP 16       // [16, 272): 256 loss buckets
#define W_CNT   8192     // u32[32768]: 4 packed u8 quarter counts
#define W_ZBF   49152    // z_bf16 (8MB), 16B-aligned
#define QCAP    16

#define DELTA    1.5e-4f   // export guard; >= 4x (2*bf16err + tie-span)
#define DWIN     64        // dot16 filter window (1.22e-4)
#define FLOATMAX 3.402823466e+38f

using short8 = __attribute__((ext_vector_type(8))) short;   // 8 bf16
using f32x4  = __attribute__((ext_vector_type(4))) float;

static __device__ __forceinline__ unsigned int pack2_bf16(float lo, float hi) {
    unsigned int ul = __builtin_bit_cast(unsigned int, lo);
    unsigned int uh = __builtin_bit_cast(unsigned int, hi);
    ul = (ul + 0x7fffu + ((ul >> 16) & 1u)) >> 16;   // RNE to bf16
    uh = (uh + 0x7fffu + ((uh >> 16) & 1u)) >> 16;
    return ul | (uh << 16);
}
// order-preserving float<->u32 map (atomicMax-able)
static __device__ __forceinline__ unsigned int enc_f32(float f) {
    unsigned int u = __builtin_bit_cast(unsigned int, f);
    return (u & 0x80000000u) ? ~u : (u | 0x80000000u);
}
static __device__ __forceinline__ float dec_f32(unsigned int u) {
    unsigned int b = (u & 0x80000000u) ? (u ^ 0x80000000u) : ~u;
    return __builtin_bit_cast(float, b);
}

// ---------------------------------------------------------------------------
// cvt + init: z->bf16 (ws), embed->bf16, seed new_size/new_sum, zero cnt,
// loss buckets, rowmax.
// ---------------------------------------------------------------------------
__global__ __launch_bounds__(256)
void vq_cvt(const float* __restrict__ z, const float* __restrict__ embed,
            const float* __restrict__ cs, const float* __restrict__ ea,
            float* __restrict__ out, float* __restrict__ ws) {
    int gid = blockIdx.x * 256 + threadIdx.x;
    if (gid < 524288) {
        const float4* s = (const float4*)z + (size_t)gid * 2;
        float4 a = s[0], b = s[1];
        uint4 wv;
        wv.x = pack2_bf16(a.x, a.y); wv.y = pack2_bf16(a.z, a.w);
        wv.z = pack2_bf16(b.x, b.y); wv.w = pack2_bf16(b.z, b.w);
        ((uint4*)(ws + W_ZBF))[gid] = wv;
    } else if (gid < 655360) {
        int j = gid - 524288;
        const float4* s = (const float4*)embed + (size_t)j * 2;
        float4 a = s[0], b = s[1];
        uint4 wv;
        wv.x = pack2_bf16(a.x, a.y); wv.y = pack2_bf16(a.z, a.w);
        wv.z = pack2_bf16(b.x, b.y); wv.w = pack2_bf16(b.z, b.w);
        ((uint4*)(out + O_EBF))[j] = wv;
    } else if (gid < 1703936) {
        int j = gid - 655360;
        out[O_NSUM + j] = 0.99f * ea[j];
    } else if (gid < 1712128) {
        int j = gid - 1703936;
        out[O_NSZ + j] = 0.99f * cs[j];
    } else if (gid < 1720320) {
        int j = gid - 1712128;
        ((uint4*)(ws + W_CNT))[j] = make_uint4(0u, 0u, 0u, 0u);
    } else if (gid < 1720576) {
        ws[W_LOSSP + (gid - 1720320)] = 0.f;
    } else if (gid < 1728768) {
        int j = gid - 1720576;
        ((uint4*)(out + O_RMX))[j] = make_uint4(0u, 0u, 0u, 0u);
    }
}

// ---------------------------------------------------------------------------
// Pass 1: FULL per-row max bf16-dot. Grid 512: block = (rb = bid>>2,
// cq = bid&3) -> 256 rows x 2048 codes, 32 chunks of 64. 8 waves (512 thr):
// chf = w&1 (32-code half), rh = w>>1 (64-row quarter); 2mf x 4nf per wave.
// Ring-4 LDS via global_load_lds (wave-uniform dest + lane-implicit offset),
// prefetch-2, counted vmcnt, one barrier per chunk, setprio around MFMA.
// ---------------------------------------------------------------------------
__global__ __launch_bounds__(512, 2)
void vq_max(const uint4* __restrict__ zb4, const uint4* __restrict__ eb4,
            unsigned int* __restrict__ rowmax) {
    __shared__ uint4 els[4 * 1024];          // 4 x 16 KiB ring

    const int t    = threadIdx.x;
    const int lane = t & 63;
    const int w    = __builtin_amdgcn_readfirstlane(t >> 6);   // 0..7
    const int g    = lane >> 4;
    const int q    = lane & 15;
    const int chf  = w & 1;
    const int rh   = w >> 1;        // 0..3
    const int rb   = blockIdx.x >> 2;
    const int cq   = blockIdx.x & 3;
    const int row0 = rb * 256;

    const uint4* gsrc[2];
    #pragma unroll
    for (int i = 0; i < 2; ++i) {
        int s_lin = i * 512 + w * 64 + lane;        // 0..1023 per-lane src
        int c = s_lin >> 4, gg = s_lin & 15;
        gsrc[i] = eb4 + (size_t)cq * 32768 + c * 16 + (gg ^ (c & 7));
    }

#define STAGE(CH)                                                             \
    {                                                                         \
        _Pragma("unroll")                                                     \
        for (int i = 0; i < 2; ++i)                                           \
            __builtin_amdgcn_global_load_lds(                                 \
                (const __attribute__((address_space(1))) unsigned int*)       \
                    (gsrc[i] + (size_t)(CH) * 1024),                          \
                (__attribute__((address_space(3))) unsigned int*)             \
                    &els[((CH) & 3) * 1024 + i * 512 + (w << 6)],             \
                16, 0, 0);                                                    \
    }

    short8 bx[4][4];
    #pragma unroll
    for (int nf = 0; nf < 4; ++nf) {
        const uint4* zp = zb4 + (size_t)(row0 + rh * 64 + nf * 16 + q) * 16;
        #pragma unroll
        for (int ks = 0; ks < 4; ++ks)
            bx[nf][ks] = __builtin_bit_cast(short8, zp[ks * 4 + g]);
    }

    STAGE(0);
    STAGE(1);

    float cmx[4] = { -FLOATMAX, -FLOATMAX, -FLOATMAX, -FLOATMAX };

    for (int ch = 0; ch < 32; ++ch) {
        if (ch < 30) {
            STAGE(ch + 2);
            asm volatile("s_waitcnt vmcnt(4)" ::: "memory");
        } else if (ch == 30) {
            asm volatile("s_waitcnt vmcnt(2)" ::: "memory");
        } else {
            asm volatile("s_waitcnt vmcnt(0)" ::: "memory");
        }
        __builtin_amdgcn_s_barrier();

        const uint4* el = els + (ch & 3) * 1024;

        f32x4 acc[2][4];
        #pragma unroll
        for (int mf = 0; mf < 2; ++mf)
            #pragma unroll
            for (int nf = 0; nf < 4; ++nf) acc[mf][nf] = (f32x4)0.f;

        __builtin_amdgcn_s_setprio(1);
        #pragma unroll
        for (int ks = 0; ks < 4; ++ks) {
            int k8 = ks * 4 + g;
            short8 af[2];
            #pragma unroll
            for (int mf = 0; mf < 2; ++mf) {
                int cm = chf * 32 + mf * 16 + q;
                af[mf] = __builtin_bit_cast(short8, el[cm * 16 + (k8 ^ (cm & 7))]);
            }
            #pragma unroll
            for (int mf = 0; mf < 2; ++mf)
                #pragma unroll
                for (int nf = 0; nf < 4; ++nf)
                    acc[mf][nf] = __builtin_amdgcn_mfma_f32_16x16x32_bf16(
                        af[mf], bx[nf][ks], acc[mf][nf], 0, 0, 0);
        }
        __builtin_amdgcn_s_setprio(0);

        #pragma unroll
        for (int nf = 0; nf < 4; ++nf)
            #pragma unroll
            for (int mf = 0; mf < 2; ++mf)
                #pragma unroll
                for (int rg = 0; rg < 4; ++rg)
                    cmx[nf] = fmaxf(cmx[nf], acc[mf][nf][rg]);
    }
#undef STAGE

    #pragma unroll
    for (int nf = 0; nf < 4; ++nf) {
        float cm = cmx[nf];
        cm = fmaxf(cm, __shfl_xor(cm, 16, 64));
        cm = fmaxf(cm, __shfl_xor(cm, 32, 64));
        if (lane < 16)
            atomicMax(&rowmax[row0 + rh * 64 + nf * 16 + lane], enc_f32(cm));
    }
}

// ---------------------------------------------------------------------------
// Pass 2: export codes with dot > rowmax - DELTA (rowmax = TRUE max ->
// exports superset of {argmin U ties}; overflow -> quarter-scan fallback).
// Same tiling/MFMA/schedule as vq_max (dots bit-identical). ~2 exports/row
// total: direct scattered global stores (r7 proved no overfetch).
// ---------------------------------------------------------------------------
__global__ __launch_bounds__(512, 2)
void vq_export(const uint4* __restrict__ zb4, const uint4* __restrict__ eb4,
               const unsigned int* __restrict__ rowmax,
               unsigned int* __restrict__ cnt, unsigned int* __restrict__ candg) {
    __shared__ uint4 els[4 * 1024];          // 4 x 16 KiB ring
    __shared__ unsigned int cnt_l[256];

    const int t    = threadIdx.x;
    const int lane = t & 63;
    const int w    = __builtin_amdgcn_readfirstlane(t >> 6);   // 0..7
    const int g    = lane >> 4;
    const int q    = lane & 15;
    const int chf  = w & 1;
    const int rh   = w >> 1;        // 0..3
    const int rb   = blockIdx.x >> 2;
    const int cq   = blockIdx.x & 3;
    const int row0 = rb * 256;

    if (t < 256) cnt_l[t] = 0u;

    const uint4* gsrc[2];
    #pragma unroll
    for (int i = 0; i < 2; ++i) {
        int s_lin = i * 512 + w * 64 + lane;
        int c = s_lin >> 4, gg = s_lin & 15;
        gsrc[i] = eb4 + (size_t)cq * 32768 + c * 16 + (gg ^ (c & 7));
    }

#define STAGE(CH)                                                             \
    {                                                                         \
        _Pragma("unroll")                                                     \
        for (int i = 0; i < 2; ++i)                                           \
            __builtin_amdgcn_global_load_lds(                                 \
                (const __attribute__((address_space(1))) unsigned int*)       \
                    (gsrc[i] + (size_t)(CH) * 1024),                          \
                (__attribute__((address_space(3))) unsigned int*)             \
                    &els[((CH) & 3) * 1024 + i * 512 + (w << 6)],             \
                16, 0, 0);                                                    \
    }

    short8 bx[4][4];
    float  thr[4];
    #pragma unroll
    for (int nf = 0; nf < 4; ++nf) {
        int row = row0 + rh * 64 + nf * 16 + q;
        const uint4* zp = zb4 + (size_t)row * 16;
        #pragma unroll
        for (int ks = 0; ks < 4; ++ks)
            bx[nf][ks] = __builtin_bit_cast(short8, zp[ks * 4 + g]);
        thr[nf] = dec_f32(rowmax[row]) - DELTA;
    }

    STAGE(0);
    STAGE(1);
    __builtin_amdgcn_s_barrier();   // cnt_l init visible before exports

    for (int ch = 0; ch < 32; ++ch) {
        if (ch < 30) {
            STAGE(ch + 2);
            asm volatile("s_waitcnt vmcnt(4)" ::: "memory");
        } else if (ch == 30) {
            asm volatile("s_waitcnt vmcnt(2)" ::: "memory");
        } else {
            asm volatile("s_waitcnt vmcnt(0)" ::: "memory");
        }
        __builtin_amdgcn_s_barrier();

        const uint4* el = els + (ch & 3) * 1024;

        f32x4 acc[2][4];
        #pragma unroll
        for (int mf = 0; mf < 2; ++mf)
            #pragma unroll
            for (int nf = 0; nf < 4; ++nf) acc[mf][nf] = (f32x4)0.f;

        __builtin_amdgcn_s_setprio(1);
        #pragma unroll
        for (int ks = 0; ks < 4; ++ks) {
            int k8 = ks * 4 + g;
            short8 af[2];
            #pragma unroll
            for (int mf = 0; mf < 2; ++mf) {
                int cm = chf * 32 + mf * 16 + q;
                af[mf] = __builtin_bit_cast(short8, el[cm * 16 + (k8 ^ (cm & 7))]);
            }
            #pragma unroll
            for (int mf = 0; mf < 2; ++mf)
                #pragma unroll
                for (int nf = 0; nf < 4; ++nf)
                    acc[mf][nf] = __builtin_amdgcn_mfma_f32_16x16x32_bf16(
                        af[mf], bx[nf][ks], acc[mf][nf], 0, 0, 0);
        }
        __builtin_amdgcn_s_setprio(0);

        // per-lane check against the FINAL threshold; export is rare
        #pragma unroll
        for (int nf = 0; nf < 4; ++nf) {
            float cm = -FLOATMAX;
            #pragma unroll
            for (int mf = 0; mf < 2; ++mf)
                #pragma unroll
                for (int rg = 0; rg < 4; ++rg) cm = fmaxf(cm, acc[mf][nf][rg]);
            if (cm > thr[nf]) {
                int r_l = rh * 64 + nf * 16 + q;
                #pragma unroll
                for (int mf = 0; mf < 2; ++mf)
                    #pragma unroll
                    for (int rg = 0; rg < 4; ++rg) {
                        if (acc[mf][nf][rg] > thr[nf]) {
                            int code = cq * 2048 + ch * 64 + chf * 32
                                     + mf * 16 + g * 4 + rg;
                            unsigned int dot16 = (unsigned int)(int)
                                fmaf(acc[mf][nf][rg], 524288.0f, 32768.0f);
                            unsigned int slot = atomicAdd(&cnt_l[r_l], 1u);
                            if (slot < QCAP)
                                candg[(size_t)(row0 + r_l) * 128 + cq * 32 + slot]
                                    = (unsigned int)code | (dot16 << 16);
                        }
                    }
            }
        }
    }
#undef STAGE

    __syncthreads();
    if (t < 256) {
        unsigned int v = min(cnt_l[t], (unsigned int)(QCAP + 1));
        atomicAdd(&cnt[row0 + t], v << (8 * (unsigned)cq));
    }
}

// ---------------------------------------------------------------------------
// Phase 2 (merged): dot16 filter -> exact rescore (numpy-bit-exact,
// r1/r3-proven) of survivors -> idx, z_q, loss partial, EMA stats.
// Overflowed quarter -> exact scan of its 2048 codes.
// ---------------------------------------------------------------------------
__global__ __launch_bounds__(256)
void vq_rescore_gather(const float* __restrict__ z,
                       const float* __restrict__ embed,
                       const unsigned int* __restrict__ cnt,
                       const unsigned int* __restrict__ candg,
                       float* __restrict__ out, float* __restrict__ ws) {
    __shared__ float xr[4][128];
    __shared__ float lsh[4];
    const int t = threadIdx.x, w = t >> 6, lane = t & 63;
    const int row = blockIdx.x * 4 + w;

    ((float2*)xr[w])[lane] = ((const float2*)(z + (size_t)row * DIM))[lane];
    __syncthreads();

    const float4* x4 = (const float4*)xr[w];

    float s1n;
    {
        #pragma clang fp contract(off)
        float r8[8];
        float4 a = x4[0], b = x4[1];
        r8[0] = a.x * a.x; r8[1] = a.y * a.y; r8[2] = a.z * a.z; r8[3] = a.w * a.w;
        r8[4] = b.x * b.x; r8[5] = b.y * b.y; r8[6] = b.z * b.z; r8[7] = b.w * b.w;
        for (int bb = 1; bb < 16; ++bb) {
            float4 c = x4[2 * bb], d = x4[2 * bb + 1];
            r8[0] += c.x * c.x; r8[1] += c.y * c.y; r8[2] += c.z * c.z; r8[3] += c.w * c.w;
            r8[4] += d.x * d.x; r8[5] += d.y * d.y; r8[6] += d.z * d.z; r8[7] += d.w * d.w;
        }
        s1n = ((r8[0] + r8[1]) + (r8[2] + r8[3])) + ((r8[4] + r8[5]) + (r8[6] + r8[7]));
    }

    float bd = FLOATMAX;
    int   bi = 0x7fffffff;

#define EVAL_CODE(code_)                                                      \
    {                                                                         \
        const float4* ep = (const float4*)(embed + (size_t)(code_) * DIM);    \
        float dot = 0.f;                                                      \
        _Pragma("unroll 8")                                                   \
        for (int k4 = 0; k4 < 32; ++k4) {                                     \
            float4 xv = x4[k4], ev = ep[k4];                                  \
            dot = fmaf(xv.x, ev.x, dot);                                      \
            dot = fmaf(xv.y, ev.y, dot);                                      \
            dot = fmaf(xv.z, ev.z, dot);                                      \
            dot = fmaf(xv.w, ev.w, dot);                                      \
        }                                                                     \
        float d = fmaf(-2.0f, dot, s1n);                                      \
        if (d < bd || (d == bd && (code_) < bi)) { bd = d; bi = (code_); }    \
    }

    const unsigned int v = cnt[row];
    int  cq4[4];
    bool ovf[4];
    #pragma unroll
    for (int qq = 0; qq < 4; ++qq) {
        cq4[qq] = (int)((v >> (8 * qq)) & 0xffu);
        ovf[qq] = (cq4[qq] > QCAP);
    }

    const unsigned int* cl = candg + (size_t)row * 128;

    // one entry per lane: qq = lane>>4, slot = lane&15
    int qq0 = lane >> 4, sl0 = lane & 15;
    bool v0 = (!ovf[qq0]) && (sl0 < cq4[qq0]);
    unsigned int p0 = v0 ? cl[qq0 * 32 + sl0] : 0u;
    int d0 = v0 ? (int)(p0 >> 16) : -1;

    int m = d0;
    #pragma unroll
    for (int o = 32; o >= 1; o >>= 1) m = max(m, __shfl_xor(m, o, 64));

    if (v0 && d0 + DWIN >= m) { int code = (int)(p0 & 0xffffu); EVAL_CODE(code); }

    #pragma unroll
    for (int qq = 0; qq < 4; ++qq) {
        if (ovf[qq]) {
            for (int j = lane; j < 2048; j += 64) {
                int code = qq * 2048 + j;
                EVAL_CODE(code);
            }
        }
    }
#undef EVAL_CODE

    #pragma unroll
    for (int o = 32; o >= 1; o >>= 1) {
        float d2 = __shfl_xor(bd, o, 64);
        int   i2 = __shfl_xor(bi, o, 64);
        if (d2 < bd || (d2 == bd && i2 < bi)) { bd = d2; bi = i2; }
    }

    float2 zv2 = ((const float2*)xr[w])[lane];
    float2 ev2 = ((const float2*)(embed + (size_t)bi * DIM))[lane];
    float2 o2;
    o2.x = zv2.x + (ev2.x - zv2.x);     // z + (z_q - z), np op order
    o2.y = zv2.y + (ev2.y - zv2.y);
    ((float2*)(out + O_ZQ))[(size_t)row * 64 + lane] = o2;

    float dx = zv2.x - ev2.x, dy = zv2.y - ev2.y;
    float lp = dx * dx + dy * dy;
    #pragma unroll
    for (int off = 32; off >= 1; off >>= 1) lp += __shfl_down(lp, off, 64);

    atomicAdd(&out[O_NSUM + (size_t)bi * DIM + lane * 2],     0.01f * zv2.x);
    atomicAdd(&out[O_NSUM + (size_t)bi * DIM + lane * 2 + 1], 0.01f * zv2.y);
    if (lane == 0) {
        out[O_IDX + row] = (float)bi;
        atomicAdd(&out[O_NSZ + bi], 0.01f);
        lsh[w] = lp;
    }
    __syncthreads();
    if (t == 0)
        atomicAdd(&ws[W_LOSSP + (blockIdx.x & 255)],
                  (lsh[0] + lsh[1]) + (lsh[2] + lsh[3]));
}

// ---------------------------------------------------------------------------
// finalize: n = sum(new_size) -> ws[1]; loss = sum(256 buckets)/(N*D)
// ---------------------------------------------------------------------------
__global__ __launch_bounds__(256)
void vq_finalize(float* __restrict__ out, float* __restrict__ ws) {
    __shared__ float sh[256];
    const int t = threadIdx.x;

    float s = 0.f;
    for (int i = t; i < KC; i += 256) s += out[O_NSZ + i];
    sh[t] = s; __syncthreads();
    for (int o = 128; o > 0; o >>= 1) {
        if (t < o) sh[t] += sh[t + o];
        __syncthreads();
    }
    float n = sh[0];
    __syncthreads();

    sh[t] = ws[W_LOSSP + t]; __syncthreads();
    for (int o = 128; o > 0; o >>= 1) {
        if (t < o) sh[t] += sh[t + o];
        __syncthreads();
    }
    if (t == 0) {
        ws[1] = n;
        out[O_LOSS] = sh[0] / 4194304.0f;
    }
}

__global__ __launch_bounds__(256)
void vq_new_embed(float* __restrict__ out, const float* __restrict__ ws) {
    int i = blockIdx.x * 256 + threadIdx.x;
    if (i >= KC * DIM) return;
    int k = i >> 7;
    float n  = ws[1];
    float ns = out[O_NSZ + k];
    float sm = (ns + 1e-5f) / (n + 0.08192f) * n;
    out[O_NEMB + i] = out[O_NSUM + i] / sm;
}

extern "C" void kernel_launch(void* const* d_in, const int* in_sizes, int n_in,
                              void* d_out, int out_size, void* d_ws, size_t ws_size,
                              hipStream_t stream) {
    const float* z     = (const float*)d_in[0];
    const float* embed = (const float*)d_in[1];
    const float* cs    = (const float*)d_in[2];
    const float* ea    = (const float*)d_in[3];
    float* out = (float*)d_out;
    float* ws  = (float*)d_ws;
    unsigned int* cnt    = (unsigned int*)(ws + W_CNT);
    unsigned int* candg  = (unsigned int*)out;          // O_ZQ region
    unsigned int* rowmax = (unsigned int*)(out + O_RMX);

    vq_cvt<<<6753, 256, 0, stream>>>(z, embed, cs, ea, out, ws);
    vq_max<<<512, 512, 0, stream>>>((const uint4*)(ws + W_ZBF),
                                    (const uint4*)(out + O_EBF), rowmax);
    vq_export<<<512, 512, 0, stream>>>((const uint4*)(ws + W_ZBF),
                                       (const uint4*)(out + O_EBF),
                                       rowmax, cnt, candg);
    vq_rescore_gather<<<NR / 4, 256, 0, stream>>>(z, embed, cnt, candg, out, ws);
    vq_finalize<<<1, 256, 0, stream>>>(out, ws);
    vq_new_embed<<<4096, 256, 0, stream>>>(out, ws);
}